// Round 5
// baseline (487.271 us; speedup 1.0000x reference)
//
#include <hip/hip_runtime.h>
#include <hip/hip_bf16.h>
#include <math.h>

#define N_NODES 100000
#define N_EDGES 3200000
#define IN_FEATS 256
#define N_UNITS 32
#define OUT_FEATS 40

#define NPB 64                       // nodes per fine bucket
#define BSHIFT 6                     // dst >> 6 = fine bucket
#define NB 1563                      // ceil(100000/64) fine buckets
#define CAP 4096                     // max edges per fine bucket (avg 2048)

#define NC 49                        // coarse buckets (2048 nodes each)
#define CSHIFT 11                    // dst >> 11 = coarse bucket
#define CHUNK 8192                   // edges per bin block
#define NBLK ((N_EDGES + CHUNK - 1) / CHUNK)   // 391
#define WIN 128                      // fine-bucket window in pass B

// ================= K1: per-fine-bucket edge counts (LDS-aggregated) =================
__global__ void __launch_bounds__(256) count_kernel(const int* __restrict__ dst,
                                                    int* __restrict__ bucket_count) {
    __shared__ int lh[NB];
    for (int i = threadIdx.x; i < NB; i += 256) lh[i] = 0;
    __syncthreads();
    for (int e = blockIdx.x * 256 + threadIdx.x; e < N_EDGES; e += gridDim.x * 256)
        atomicAdd(&lh[dst[e] >> BSHIFT], 1);
    __syncthreads();
    for (int i = threadIdx.x; i < NB; i += 256)
        if (lh[i]) atomicAdd(&bucket_count[i], lh[i]);
}

// ================= K2: exclusive scan of fine counts; derive coarse bases =================
__global__ void __launch_bounds__(1024) scan_kernel(const int* __restrict__ bucket_count,
                                                    int* __restrict__ gbase,
                                                    int* __restrict__ gcursor,
                                                    int* __restrict__ gbaseA,
                                                    int* __restrict__ gcursorA) {
    __shared__ int ps[1024];
    int t = threadIdx.x;
    int i0 = 2 * t, i1 = 2 * t + 1;
    int a = (i0 < NB) ? bucket_count[i0] : 0;
    int b = (i1 < NB) ? bucket_count[i1] : 0;
    ps[t] = a + b;
    __syncthreads();
    for (int off = 1; off < 1024; off <<= 1) {
        int v = (t >= off) ? ps[t - off] : 0;
        __syncthreads();
        ps[t] += v;
        __syncthreads();
    }
    int excl = ps[t] - (a + b);
    if (i0 < NB) { gbase[i0] = excl; gcursor[i0] = excl; }
    if (i1 <= NB) { gbase[i1] = excl + a; if (i1 < NB) gcursor[i1] = excl + a; }
    __syncthreads();
    // coarse base c = fine base at fine id 32c (fine ids are coarse-major)
    if (t < NC) { int v = gbase[t * 32]; gbaseA[t] = v; gcursorA[t] = v; }
    if (t == NC) gbaseA[NC] = N_EDGES;
}

// ================= K3a: coarse binning (49 bins) — LDS sort + coalesced write =================
// pairsA word: src (17 bits) | dlocal11 (11 bits) << 17
__global__ void __launch_bounds__(512) binA_kernel(const int* __restrict__ src,
                                                   const int* __restrict__ dst,
                                                   int* __restrict__ gcursorA,
                                                   unsigned* __restrict__ pairsA,
                                                   int* __restrict__ outdegI) {
    __shared__ unsigned sortedA[CHUNK];      // 32 KB
    __shared__ int hist[NC];
    __shared__ int lstart[NC];
    __shared__ int cur[NC];
    __shared__ int gres[NC];
    int tid = threadIdx.x;
    int e0 = blockIdx.x * CHUNK;
    int cnt = min(CHUNK, N_EDGES - e0);
    unsigned es[16], ed[16];
    #pragma unroll
    for (int r = 0; r < 16; ++r) {
        int idx = tid + 512 * r;
        if (idx < cnt) { es[r] = src[e0 + idx]; ed[r] = dst[e0 + idx]; }
    }
    if (tid < NC) hist[tid] = 0;
    __syncthreads();
    #pragma unroll
    for (int r = 0; r < 16; ++r) {
        int idx = tid + 512 * r;
        if (idx < cnt) {
            atomicAdd(&hist[ed[r] >> CSHIFT], 1);
            atomicAdd(&outdegI[es[r]], 1);
        }
    }
    __syncthreads();
    if (tid < 64) {
        int v = (tid < NC) ? hist[tid] : 0;
        int inc = v;
        #pragma unroll
        for (int off = 1; off < 64; off <<= 1) {
            int u = __shfl_up(inc, off, 64);
            if ((tid & 63) >= off) inc += u;
        }
        if (tid < NC) {
            int ls = inc - v;
            lstart[tid] = ls;
            cur[tid] = ls;
            gres[tid] = atomicAdd(&gcursorA[tid], v) - ls;   // dest = gres[c] + i
        }
    }
    __syncthreads();
    #pragma unroll
    for (int r = 0; r < 16; ++r) {
        int idx = tid + 512 * r;
        if (idx < cnt) {
            int c = ed[r] >> CSHIFT;
            int pos = atomicAdd(&cur[c], 1);
            sortedA[pos] = es[r] | ((ed[r] & ((1u << CSHIFT) - 1)) << 17);
        }
    }
    __syncthreads();
    for (int i = tid; i < cnt; i += 512) {
        int lo = 0, hi = NC - 1;                // largest c with lstart[c] <= i
        while (lo < hi) { int mid = (lo + hi + 1) >> 1; if (lstart[mid] <= i) lo = mid; else hi = mid - 1; }
        pairsA[gres[lo] + i] = sortedA[i];
    }
}

// ================= K3b: fine binning within 128-bin window — LDS sort + coalesced write =================
// pairs word: src (low 24) | d6 << 24
__global__ void __launch_bounds__(512) binB_kernel(const unsigned* __restrict__ pairsA,
                                                   const int* __restrict__ gbaseA,
                                                   int* __restrict__ gcursor,
                                                   unsigned* __restrict__ pairs) {
    __shared__ unsigned sortedB[CHUNK];      // 32 KB
    __shared__ int hist[WIN];
    __shared__ int lstart[WIN];
    __shared__ int cur[WIN];
    __shared__ int gres[WIN];
    __shared__ int gA[NC + 1];
    int tid = threadIdx.x;
    if (tid <= NC) gA[tid] = gbaseA[tid];
    if (tid < WIN) hist[tid] = 0;
    int e0 = blockIdx.x * CHUNK;
    int cnt = min(CHUNK, N_EDGES - e0);
    __syncthreads();
    // coarse id of chunk start
    int c0 = 0;
    { int lo = 0, hi = NC - 1;
      while (lo < hi) { int mid = (lo + hi + 1) >> 1; if (gA[mid] <= e0) lo = mid; else hi = mid - 1; }
      c0 = lo; }
    int w0 = c0 * 32;
    unsigned pv[16]; short fw[16];
    int c = c0;
    #pragma unroll
    for (int r = 0; r < 16; ++r) {
        int idx = tid + 512 * r;
        if (idx < cnt) {
            int pos = e0 + idx;
            while (pos >= gA[c + 1]) ++c;
            unsigned p = pairsA[pos];
            unsigned srcid = p & 0x1FFFF;
            unsigned dl11 = (p >> 17) & 0x7FF;
            int wi = (c - c0) * 32 + (int)(dl11 >> 6);
            atomicAdd(&hist[wi], 1);
            pv[r] = srcid | ((dl11 & 63u) << 24);
            fw[r] = (short)wi;
        }
    }
    __syncthreads();
    if (tid < 64) {
        int v0 = hist[2 * tid], v1 = hist[2 * tid + 1];
        int s = v0 + v1;
        int inc = s;
        #pragma unroll
        for (int off = 1; off < 64; off <<= 1) {
            int u = __shfl_up(inc, off, 64);
            if ((tid & 63) >= off) inc += u;
        }
        int excl = inc - s;
        lstart[2 * tid] = excl;      cur[2 * tid] = excl;
        lstart[2 * tid + 1] = excl + v0; cur[2 * tid + 1] = excl + v0;
        int f0 = w0 + 2 * tid, f1 = f0 + 1;
        gres[2 * tid]     = (f0 < NB) ? (atomicAdd(&gcursor[f0], v0) - excl) : 0;
        gres[2 * tid + 1] = (f1 < NB) ? (atomicAdd(&gcursor[f1], v1) - (excl + v0)) : 0;
    }
    __syncthreads();
    #pragma unroll
    for (int r = 0; r < 16; ++r) {
        int idx = tid + 512 * r;
        if (idx < cnt) {
            int pos = atomicAdd(&cur[fw[r]], 1);
            sortedB[pos] = pv[r];
        }
    }
    __syncthreads();
    for (int i = tid; i < cnt; i += 512) {
        int lo = 0, hi = WIN - 1;               // largest wi with lstart[wi] <= i
        while (lo < hi) { int mid = (lo + hi + 1) >> 1; if (lstart[mid] <= i) lo = mid; else hi = mid - 1; }
        pairs[gres[lo] + i] = sortedB[i];
    }
}

// ================= K4: h[n,32] = (x[n,:] @ W1) * inv_out[n] =================
__global__ void __launch_bounds__(256) gemm1_kernel(
        const float* __restrict__ x, const float* __restrict__ W1,
        const int* __restrict__ outdegI, float* __restrict__ h, int N) {
    __shared__ float Ws[IN_FEATS * N_UNITS];  // 32 KB
    for (int idx = threadIdx.x; idx < IN_FEATS * N_UNITS; idx += 256)
        Ws[idx] = W1[idx];
    __syncthreads();
    unsigned t = blockIdx.x * 256 + threadIdx.x;
    unsigned n = t >> 2;
    if (n >= (unsigned)N) return;
    unsigned j0 = (t & 3) * 8;
    float acc[8] = {0, 0, 0, 0, 0, 0, 0, 0};
    const float4* xr = (const float4*)(x + (size_t)n * IN_FEATS);
    #pragma unroll 4
    for (int k4 = 0; k4 < IN_FEATS / 4; ++k4) {
        float4 xv = xr[k4];
        const float* wk = Ws + (k4 * 4) * N_UNITS + j0;
        #pragma unroll
        for (int jj = 0; jj < 8; ++jj) acc[jj] = fmaf(xv.x, wk[jj], acc[jj]);
        #pragma unroll
        for (int jj = 0; jj < 8; ++jj) acc[jj] = fmaf(xv.y, wk[N_UNITS + jj], acc[jj]);
        #pragma unroll
        for (int jj = 0; jj < 8; ++jj) acc[jj] = fmaf(xv.z, wk[2 * N_UNITS + jj], acc[jj]);
        #pragma unroll
        for (int jj = 0; jj < 8; ++jj) acc[jj] = fmaf(xv.w, wk[3 * N_UNITS + jj], acc[jj]);
    }
    float io = rsqrtf(fmaxf((float)outdegI[n], 1.0f));
    float* hr = h + (size_t)n * N_UNITS + j0;
    #pragma unroll
    for (int jj = 0; jj < 8; ++jj) hr[jj] = acc[jj] * io;
}

// ================= K5/K6: bucketed gather — LDS counting sort + register accumulation =================
template <bool LAYER1>
__global__ void __launch_bounds__(256) gather_kernel(
        const float* __restrict__ in, const unsigned* __restrict__ pairs,
        const int* __restrict__ gbase, const int* __restrict__ outdegI,
        const float* __restrict__ b1, float* __restrict__ outbuf,
        float* __restrict__ inv_in) {
    __shared__ int sorted[CAP];        // 16 KB: src ids grouped by local dst
    __shared__ int cnt[NPB];
    __shared__ int start[NPB + 1];
    __shared__ int cur[NPB];
    __shared__ float b1s[N_UNITS];
    int tid = threadIdx.x;
    int b = blockIdx.x;
    int ebeg = gbase[b];
    int ecnt = min(gbase[b + 1] - ebeg, CAP);
    if (tid < NPB) cnt[tid] = 0;
    if (LAYER1 && tid < N_UNITS) b1s[tid] = b1[tid];
    __syncthreads();

    unsigned stash[16];
    #pragma unroll
    for (int r = 0; r < 16; ++r) {
        int idx = tid + 256 * r;
        if (idx < ecnt) {
            unsigned p = pairs[ebeg + idx];
            stash[r] = p;
            atomicAdd(&cnt[p >> 24], 1);
        }
    }
    __syncthreads();

    if (tid < 64) {
        int v = cnt[tid];
        int inc = v;
        #pragma unroll
        for (int off = 1; off < 64; off <<= 1) {
            int u = __shfl_up(inc, off, 64);
            if (tid >= off) inc += u;
        }
        start[tid + 1] = inc;
        cur[tid] = inc - v;
        if (tid == 0) start[0] = 0;
    }
    __syncthreads();

    #pragma unroll
    for (int r = 0; r < 16; ++r) {
        int idx = tid + 256 * r;
        if (idx < ecnt) {
            unsigned p = stash[r];
            int pos = atomicAdd(&cur[p >> 24], 1);
            sorted[pos] = (int)(p & 0xFFFFFF);
        }
    }
    __syncthreads();

    int w = tid >> 6;
    int lane = tid & 63;
    int q = lane & 7;
    int eo = lane >> 3;
    int nd0 = b * NPB;
    #pragma unroll 1
    for (int p = 0; p < 16; ++p) {
        int nd = w * 16 + p;
        int n = nd0 + nd;
        int beg = start[nd];
        int end = start[nd + 1];
        float ax0 = 0.f, ay0 = 0.f, az0 = 0.f, aw0 = 0.f;
        float ax1 = 0.f, ay1 = 0.f, az1 = 0.f, aw1 = 0.f;
        int e = beg + eo;
        for (; e + 8 < end; e += 16) {
            int s0 = sorted[e];
            int s1 = sorted[e + 8];
            float4 v0 = *(const float4*)(in + (size_t)s0 * N_UNITS + q * 4);
            float4 v1 = *(const float4*)(in + (size_t)s1 * N_UNITS + q * 4);
            ax0 += v0.x; ay0 += v0.y; az0 += v0.z; aw0 += v0.w;
            ax1 += v1.x; ay1 += v1.y; az1 += v1.z; aw1 += v1.w;
        }
        if (e < end) {
            float4 v = *(const float4*)(in + (size_t)sorted[e] * N_UNITS + q * 4);
            ax0 += v.x; ay0 += v.y; az0 += v.z; aw0 += v.w;
        }
        e += 8;
        if (e < end) {
            float4 v = *(const float4*)(in + (size_t)sorted[e] * N_UNITS + q * 4);
            ax1 += v.x; ay1 += v.y; az1 += v.z; aw1 += v.w;
        }
        float sx = ax0 + ax1, sy = ay0 + ay1, sz = az0 + az1, sw = aw0 + aw1;
        #pragma unroll
        for (int st = 8; st < 64; st <<= 1) {
            sx += __shfl_xor(sx, st, 64);
            sy += __shfl_xor(sy, st, 64);
            sz += __shfl_xor(sz, st, 64);
            sw += __shfl_xor(sw, st, 64);
        }
        if (eo == 0 && n < N_NODES) {
            if (LAYER1) {
                float ii = rsqrtf(fmaxf((float)(end - beg), 1.0f));
                float io = rsqrtf(fmaxf((float)outdegI[n], 1.0f));
                float4 r;
                r.x = fmaxf(fmaf(sx, ii, b1s[q * 4 + 0]), 0.0f) * io;
                r.y = fmaxf(fmaf(sy, ii, b1s[q * 4 + 1]), 0.0f) * io;
                r.z = fmaxf(fmaf(sz, ii, b1s[q * 4 + 2]), 0.0f) * io;
                r.w = fmaxf(fmaf(sw, ii, b1s[q * 4 + 3]), 0.0f) * io;
                *(float4*)(outbuf + (size_t)n * N_UNITS + q * 4) = r;
                if (q == 0) inv_in[n] = ii;
            } else {
                *(float4*)(outbuf + (size_t)n * N_UNITS + q * 4) =
                    make_float4(sx, sy, sz, sw);
            }
        }
    }
}

// ================= K7: v = (agg2 @ W2)*inv_in + b2 ; out = log_softmax(v) =================
__global__ void __launch_bounds__(256) finalize_kernel(
        const float* __restrict__ agg2, const float* __restrict__ inv_in,
        const float* __restrict__ W2, const float* __restrict__ b2,
        float* __restrict__ out, int N) {
    __shared__ float W2s[N_UNITS * OUT_FEATS];
    __shared__ float b2s[OUT_FEATS];
    for (int i = threadIdx.x; i < N_UNITS * OUT_FEATS; i += 256) W2s[i] = W2[i];
    if (threadIdx.x < OUT_FEATS) b2s[threadIdx.x] = b2[threadIdx.x];
    __syncthreads();
    int n = blockIdx.x * 256 + threadIdx.x;
    if (n >= N) return;
    float a[N_UNITS];
    const float4* ar = (const float4*)(agg2 + (size_t)n * N_UNITS);
    #pragma unroll
    for (int qq = 0; qq < N_UNITS / 4; ++qq) {
        float4 v = ar[qq];
        a[qq * 4 + 0] = v.x; a[qq * 4 + 1] = v.y; a[qq * 4 + 2] = v.z; a[qq * 4 + 3] = v.w;
    }
    float ii = inv_in[n];
    float s[OUT_FEATS];
    #pragma unroll
    for (int o = 0; o < OUT_FEATS; ++o) s[o] = 0.0f;
    #pragma unroll
    for (int k = 0; k < N_UNITS; ++k) {
        float ak = a[k];
        #pragma unroll
        for (int o = 0; o < OUT_FEATS; ++o) s[o] = fmaf(ak, W2s[k * OUT_FEATS + o], s[o]);
    }
    float mx = -INFINITY;
    #pragma unroll
    for (int o = 0; o < OUT_FEATS; ++o) {
        s[o] = fmaf(s[o], ii, b2s[o]);
        mx = fmaxf(mx, s[o]);
    }
    float sum = 0.0f;
    #pragma unroll
    for (int o = 0; o < OUT_FEATS; ++o) sum += __expf(s[o] - mx);
    float lse = mx + __logf(sum);
    #pragma unroll
    for (int o = 0; o < OUT_FEATS; ++o) s[o] -= lse;
    float4* orow4 = (float4*)(out + (size_t)n * OUT_FEATS);
    #pragma unroll
    for (int qq = 0; qq < OUT_FEATS / 4; ++qq)
        orow4[qq] = make_float4(s[qq * 4], s[qq * 4 + 1], s[qq * 4 + 2], s[qq * 4 + 3]);
}

extern "C" void kernel_launch(void* const* d_in, const int* in_sizes, int n_in,
                              void* d_out, int out_size, void* d_ws, size_t ws_size,
                              hipStream_t stream) {
    const float* x   = (const float*)d_in[0];
    const float* W1  = (const float*)d_in[1];
    const float* b1  = (const float*)d_in[2];
    const float* W2  = (const float*)d_in[3];
    const float* b2  = (const float*)d_in[4];
    const int*   src = (const int*)d_in[5];
    const int*   dst = (const int*)d_in[6];
    float* out = (float*)d_out;

    // -------- workspace layout --------
    char* base = (char*)d_ws;
    int*      outdegI      = (int*)(base);                  // [N]      400000 B
    int*      bucket_count = (int*)(base + 400000L);        // [NB]     (slot to 408192)
    int*      gbaseA       = (int*)(base + 406400L);        // [NC+1]   in slot slack
    int*      gcursorA     = (int*)(base + 406912L);        // [NC]     in slot slack
    int*      gbase        = (int*)(base + 408192L);        // [NB+1]   8192 B slot
    int*      gcursor      = (int*)(base + 416384L);        // [NB]     8192 B slot
    float*    inv_in       = (float*)(base + 424576L);      // [N]      400000 B
    unsigned* pairs        = (unsigned*)(base + 824576L);   // [E]      12.8 MB
    float*    h            = (float*)(base + 13624576L);    // [N*32] — aliased by pairsA
    float*    rprime       = (float*)(base + 26424576L);    // [N*32]
    float*    agg2         = (float*)(base + 39224576L);    // [N*32]
    unsigned* pairsA       = (unsigned*)h;                  // dead before gemm1 writes h

    // zero outdegI + bucket_count slot
    hipMemsetAsync(outdegI, 0, 408192L, stream);

    count_kernel<<<512, 256, 0, stream>>>(dst, bucket_count);
    scan_kernel<<<1, 1024, 0, stream>>>(bucket_count, gbase, gcursor, gbaseA, gcursorA);
    binA_kernel<<<NBLK, 512, 0, stream>>>(src, dst, gcursorA, pairsA, outdegI);
    binB_kernel<<<NBLK, 512, 0, stream>>>(pairsA, gbaseA, gcursor, pairs);

    gemm1_kernel<<<(N_NODES * 4 + 255) / 256, 256, 0, stream>>>(x, W1, outdegI, h, N_NODES);

    gather_kernel<true><<<NB, 256, 0, stream>>>(h, pairs, gbase, outdegI, b1, rprime, inv_in);
    gather_kernel<false><<<NB, 256, 0, stream>>>(rprime, pairs, gbase, outdegI, b1, agg2, inv_in);

    finalize_kernel<<<(N_NODES + 255) / 256, 256, 0, stream>>>(agg2, inv_in, W2, b2, out, N_NODES);
}

// Round 6
// 439.187 us; speedup vs baseline: 1.1095x; 1.1095x over previous
//
#include <hip/hip_runtime.h>
#include <hip/hip_bf16.h>
#include <math.h>

#define N_NODES 100000
#define N_EDGES 3200000
#define IN_FEATS 256
#define N_UNITS 32
#define OUT_FEATS 40

#define NPB 64                       // nodes per fine bucket
#define BSHIFT 6                     // dst >> 6 = fine bucket
#define NB 1563                      // ceil(100000/64) fine buckets
#define CAP 4096                     // max edges per fine bucket (avg 2048)

#define NC 49                        // coarse buckets (2048 nodes each)
#define CSHIFT 11                    // dst >> 11 = coarse bucket
#define CHUNK 8192                   // edges per bin block
#define NBLK ((N_EDGES + CHUNK - 1) / CHUNK)   // 391
#define WIN 128                      // fine-bucket window in pass B

#define ODS 8192                     // outdeg: nodes per slice (32 KB LDS)
#define NSL ((N_NODES + ODS - 1) / ODS)       // 13
#define OD_STRIPES 24

// ================= K0a: outdeg histogram — slice-filtered, no global atomics =================
__global__ void __launch_bounds__(256) outdeg_hist_kernel(const int* __restrict__ src,
                                                          int* __restrict__ partials) {
    __shared__ int lh[ODS];          // 32 KB
    int slice = blockIdx.x / OD_STRIPES;
    int stripe = blockIdx.x % OD_STRIPES;
    for (int i = threadIdx.x; i < ODS; i += 256) lh[i] = 0;
    __syncthreads();
    int lo = slice * ODS;
    const int4* s4 = (const int4*)src;
    const int total4 = N_EDGES / 4;
    for (int i = stripe * 256 + threadIdx.x; i < total4; i += OD_STRIPES * 256) {
        int4 v = s4[i];
        unsigned a = (unsigned)(v.x - lo); if (a < ODS) atomicAdd(&lh[a], 1);
        unsigned b = (unsigned)(v.y - lo); if (b < ODS) atomicAdd(&lh[b], 1);
        unsigned c = (unsigned)(v.z - lo); if (c < ODS) atomicAdd(&lh[c], 1);
        unsigned d = (unsigned)(v.w - lo); if (d < ODS) atomicAdd(&lh[d], 1);
    }
    __syncthreads();
    int* dstp = partials + (size_t)(slice * OD_STRIPES + stripe) * ODS;
    for (int i = threadIdx.x; i < ODS; i += 256) dstp[i] = lh[i];
}

// ================= K0b: reduce partials -> outdegI =================
__global__ void __launch_bounds__(256) outdeg_reduce_kernel(const int* __restrict__ partials,
                                                            int* __restrict__ outdegI) {
    int n = blockIdx.x * 256 + threadIdx.x;
    if (n >= N_NODES) return;
    int slice = n / ODS, off = n & (ODS - 1);
    const int* p = partials + (size_t)slice * OD_STRIPES * ODS + off;
    int s = 0;
    #pragma unroll
    for (int j = 0; j < OD_STRIPES; ++j) s += p[j * ODS];
    outdegI[n] = s;
}

// ================= K1: per-fine-bucket edge counts (LDS-aggregated) =================
__global__ void __launch_bounds__(256) count_kernel(const int* __restrict__ dst,
                                                    int* __restrict__ bucket_count) {
    __shared__ int lh[NB];
    for (int i = threadIdx.x; i < NB; i += 256) lh[i] = 0;
    __syncthreads();
    const int4* d4 = (const int4*)dst;
    const int total4 = N_EDGES / 4;
    for (int i = blockIdx.x * 256 + threadIdx.x; i < total4; i += gridDim.x * 256) {
        int4 v = d4[i];
        atomicAdd(&lh[v.x >> BSHIFT], 1);
        atomicAdd(&lh[v.y >> BSHIFT], 1);
        atomicAdd(&lh[v.z >> BSHIFT], 1);
        atomicAdd(&lh[v.w >> BSHIFT], 1);
    }
    __syncthreads();
    for (int i = threadIdx.x; i < NB; i += 256)
        if (lh[i]) atomicAdd(&bucket_count[i], lh[i]);
}

// ================= K2: exclusive scan of fine counts; derive coarse bases =================
__global__ void __launch_bounds__(1024) scan_kernel(const int* __restrict__ bucket_count,
                                                    int* __restrict__ gbase,
                                                    int* __restrict__ gcursor,
                                                    int* __restrict__ gbaseA,
                                                    int* __restrict__ gcursorA) {
    __shared__ int ps[1024];
    int t = threadIdx.x;
    int i0 = 2 * t, i1 = 2 * t + 1;
    int a = (i0 < NB) ? bucket_count[i0] : 0;
    int b = (i1 < NB) ? bucket_count[i1] : 0;
    ps[t] = a + b;
    __syncthreads();
    for (int off = 1; off < 1024; off <<= 1) {
        int v = (t >= off) ? ps[t - off] : 0;
        __syncthreads();
        ps[t] += v;
        __syncthreads();
    }
    int excl = ps[t] - (a + b);
    if (i0 < NB) { gbase[i0] = excl; gcursor[i0] = excl; }
    if (i1 <= NB) { gbase[i1] = excl + a; if (i1 < NB) gcursor[i1] = excl + a; }
    __syncthreads();
    if (t < NC) { int v = gbase[t * 32]; gbaseA[t] = v; gcursorA[t] = v; }
    if (t == NC) gbaseA[NC] = N_EDGES;
}

// ================= K3a: coarse binning (49 bins) — LDS sort + coalesced write =================
// pairsA word: src (17 bits) | dlocal11 (11 bits) << 17
__global__ void __launch_bounds__(512) binA_kernel(const int* __restrict__ src,
                                                   const int* __restrict__ dst,
                                                   int* __restrict__ gcursorA,
                                                   unsigned* __restrict__ pairsA) {
    __shared__ unsigned sortedA[CHUNK];      // 32 KB
    __shared__ int hist[NC];
    __shared__ int lstart[NC];
    __shared__ int cur[NC];
    __shared__ int gres[NC];
    int tid = threadIdx.x;
    int e0 = blockIdx.x * CHUNK;
    int cnt = min(CHUNK, N_EDGES - e0);
    unsigned es[16], ed[16];
    #pragma unroll
    for (int r = 0; r < 16; ++r) {
        int idx = tid + 512 * r;
        if (idx < cnt) { es[r] = src[e0 + idx]; ed[r] = dst[e0 + idx]; }
    }
    if (tid < NC) hist[tid] = 0;
    __syncthreads();
    #pragma unroll
    for (int r = 0; r < 16; ++r) {
        int idx = tid + 512 * r;
        if (idx < cnt) atomicAdd(&hist[ed[r] >> CSHIFT], 1);
    }
    __syncthreads();
    if (tid < 64) {
        int v = (tid < NC) ? hist[tid] : 0;
        int inc = v;
        #pragma unroll
        for (int off = 1; off < 64; off <<= 1) {
            int u = __shfl_up(inc, off, 64);
            if ((tid & 63) >= off) inc += u;
        }
        if (tid < NC) {
            int ls = inc - v;
            lstart[tid] = ls;
            cur[tid] = ls;
            gres[tid] = atomicAdd(&gcursorA[tid], v) - ls;   // dest = gres[c] + i
        }
    }
    __syncthreads();
    #pragma unroll
    for (int r = 0; r < 16; ++r) {
        int idx = tid + 512 * r;
        if (idx < cnt) {
            int c = ed[r] >> CSHIFT;
            int pos = atomicAdd(&cur[c], 1);
            sortedA[pos] = es[r] | ((ed[r] & ((1u << CSHIFT) - 1)) << 17);
        }
    }
    __syncthreads();
    for (int i = tid; i < cnt; i += 512) {
        int lo = 0, hi = NC - 1;                // largest c with lstart[c] <= i
        while (lo < hi) { int mid = (lo + hi + 1) >> 1; if (lstart[mid] <= i) lo = mid; else hi = mid - 1; }
        pairsA[gres[lo] + i] = sortedA[i];
    }
}

// ================= K3b: fine binning within 128-bin window — LDS sort + coalesced write =================
// pairs word: src (low 24) | d6 << 24
__global__ void __launch_bounds__(512) binB_kernel(const unsigned* __restrict__ pairsA,
                                                   const int* __restrict__ gbaseA,
                                                   int* __restrict__ gcursor,
                                                   unsigned* __restrict__ pairs) {
    __shared__ unsigned sortedB[CHUNK];      // 32 KB
    __shared__ int hist[WIN];
    __shared__ int lstart[WIN];
    __shared__ int cur[WIN];
    __shared__ int gres[WIN];
    __shared__ int gA[NC + 1];
    int tid = threadIdx.x;
    if (tid <= NC) gA[tid] = gbaseA[tid];
    if (tid < WIN) hist[tid] = 0;
    int e0 = blockIdx.x * CHUNK;
    int cnt = min(CHUNK, N_EDGES - e0);
    __syncthreads();
    int c0 = 0;
    { int lo = 0, hi = NC - 1;
      while (lo < hi) { int mid = (lo + hi + 1) >> 1; if (gA[mid] <= e0) lo = mid; else hi = mid - 1; }
      c0 = lo; }
    int w0 = c0 * 32;
    unsigned pv[16]; short fw[16];
    int c = c0;
    #pragma unroll
    for (int r = 0; r < 16; ++r) {
        int idx = tid + 512 * r;
        if (idx < cnt) {
            int pos = e0 + idx;
            while (pos >= gA[c + 1]) ++c;
            unsigned p = pairsA[pos];
            unsigned srcid = p & 0x1FFFF;
            unsigned dl11 = (p >> 17) & 0x7FF;
            int wi = (c - c0) * 32 + (int)(dl11 >> 6);
            atomicAdd(&hist[wi], 1);
            pv[r] = srcid | ((dl11 & 63u) << 24);
            fw[r] = (short)wi;
        }
    }
    __syncthreads();
    if (tid < 64) {
        int v0 = hist[2 * tid], v1 = hist[2 * tid + 1];
        int s = v0 + v1;
        int inc = s;
        #pragma unroll
        for (int off = 1; off < 64; off <<= 1) {
            int u = __shfl_up(inc, off, 64);
            if ((tid & 63) >= off) inc += u;
        }
        int excl = inc - s;
        lstart[2 * tid] = excl;      cur[2 * tid] = excl;
        lstart[2 * tid + 1] = excl + v0; cur[2 * tid + 1] = excl + v0;
        int f0 = w0 + 2 * tid, f1 = f0 + 1;
        gres[2 * tid]     = (f0 < NB) ? (atomicAdd(&gcursor[f0], v0) - excl) : 0;
        gres[2 * tid + 1] = (f1 < NB) ? (atomicAdd(&gcursor[f1], v1) - (excl + v0)) : 0;
    }
    __syncthreads();
    #pragma unroll
    for (int r = 0; r < 16; ++r) {
        int idx = tid + 512 * r;
        if (idx < cnt) {
            int pos = atomicAdd(&cur[fw[r]], 1);
            sortedB[pos] = pv[r];
        }
    }
    __syncthreads();
    for (int i = tid; i < cnt; i += 512) {
        int lo = 0, hi = WIN - 1;
        while (lo < hi) { int mid = (lo + hi + 1) >> 1; if (lstart[mid] <= i) lo = mid; else hi = mid - 1; }
        pairs[gres[lo] + i] = sortedB[i];
    }
}

// ================= K4: h[n,32] = (x[n,:] @ W1) * inv_out[n] =================
__global__ void __launch_bounds__(256) gemm1_kernel(
        const float* __restrict__ x, const float* __restrict__ W1,
        const int* __restrict__ outdegI, float* __restrict__ h, int N) {
    __shared__ float Ws[IN_FEATS * N_UNITS];  // 32 KB
    for (int idx = threadIdx.x; idx < IN_FEATS * N_UNITS; idx += 256)
        Ws[idx] = W1[idx];
    __syncthreads();
    unsigned t = blockIdx.x * 256 + threadIdx.x;
    unsigned n = t >> 2;
    if (n >= (unsigned)N) return;
    unsigned j0 = (t & 3) * 8;
    float acc[8] = {0, 0, 0, 0, 0, 0, 0, 0};
    const float4* xr = (const float4*)(x + (size_t)n * IN_FEATS);
    #pragma unroll 4
    for (int k4 = 0; k4 < IN_FEATS / 4; ++k4) {
        float4 xv = xr[k4];
        const float* wk = Ws + (k4 * 4) * N_UNITS + j0;
        #pragma unroll
        for (int jj = 0; jj < 8; ++jj) acc[jj] = fmaf(xv.x, wk[jj], acc[jj]);
        #pragma unroll
        for (int jj = 0; jj < 8; ++jj) acc[jj] = fmaf(xv.y, wk[N_UNITS + jj], acc[jj]);
        #pragma unroll
        for (int jj = 0; jj < 8; ++jj) acc[jj] = fmaf(xv.z, wk[2 * N_UNITS + jj], acc[jj]);
        #pragma unroll
        for (int jj = 0; jj < 8; ++jj) acc[jj] = fmaf(xv.w, wk[3 * N_UNITS + jj], acc[jj]);
    }
    float io = rsqrtf(fmaxf((float)outdegI[n], 1.0f));
    float* hr = h + (size_t)n * N_UNITS + j0;
    #pragma unroll
    for (int jj = 0; jj < 8; ++jj) hr[jj] = acc[jj] * io;
}

// ================= K5/K6: bucketed gather — LDS counting sort + register accumulation =================
template <bool LAYER1>
__global__ void __launch_bounds__(256) gather_kernel(
        const float* __restrict__ in, const unsigned* __restrict__ pairs,
        const int* __restrict__ gbase, const int* __restrict__ outdegI,
        const float* __restrict__ b1, float* __restrict__ outbuf,
        float* __restrict__ inv_in) {
    __shared__ int sorted[CAP];        // 16 KB: src ids grouped by local dst
    __shared__ int cnt[NPB];
    __shared__ int start[NPB + 1];
    __shared__ int cur[NPB];
    __shared__ float b1s[N_UNITS];
    int tid = threadIdx.x;
    int b = blockIdx.x;
    int ebeg = gbase[b];
    int ecnt = min(gbase[b + 1] - ebeg, CAP);
    if (tid < NPB) cnt[tid] = 0;
    if (LAYER1 && tid < N_UNITS) b1s[tid] = b1[tid];
    __syncthreads();

    unsigned stash[16];
    #pragma unroll
    for (int r = 0; r < 16; ++r) {
        int idx = tid + 256 * r;
        if (idx < ecnt) {
            unsigned p = pairs[ebeg + idx];
            stash[r] = p;
            atomicAdd(&cnt[p >> 24], 1);
        }
    }
    __syncthreads();

    if (tid < 64) {
        int v = cnt[tid];
        int inc = v;
        #pragma unroll
        for (int off = 1; off < 64; off <<= 1) {
            int u = __shfl_up(inc, off, 64);
            if (tid >= off) inc += u;
        }
        start[tid + 1] = inc;
        cur[tid] = inc - v;
        if (tid == 0) start[0] = 0;
    }
    __syncthreads();

    #pragma unroll
    for (int r = 0; r < 16; ++r) {
        int idx = tid + 256 * r;
        if (idx < ecnt) {
            unsigned p = stash[r];
            int pos = atomicAdd(&cur[p >> 24], 1);
            sorted[pos] = (int)(p & 0xFFFFFF);
        }
    }
    __syncthreads();

    int w = tid >> 6;
    int lane = tid & 63;
    int q = lane & 7;
    int eo = lane >> 3;
    int nd0 = b * NPB;
    #pragma unroll 1
    for (int p = 0; p < 16; ++p) {
        int nd = w * 16 + p;
        int n = nd0 + nd;
        int beg = start[nd];
        int end = start[nd + 1];
        float ax0 = 0.f, ay0 = 0.f, az0 = 0.f, aw0 = 0.f;
        float ax1 = 0.f, ay1 = 0.f, az1 = 0.f, aw1 = 0.f;
        int e = beg + eo;
        for (; e + 8 < end; e += 16) {
            int s0 = sorted[e];
            int s1 = sorted[e + 8];
            float4 v0 = *(const float4*)(in + (size_t)s0 * N_UNITS + q * 4);
            float4 v1 = *(const float4*)(in + (size_t)s1 * N_UNITS + q * 4);
            ax0 += v0.x; ay0 += v0.y; az0 += v0.z; aw0 += v0.w;
            ax1 += v1.x; ay1 += v1.y; az1 += v1.z; aw1 += v1.w;
        }
        if (e < end) {
            float4 v = *(const float4*)(in + (size_t)sorted[e] * N_UNITS + q * 4);
            ax0 += v.x; ay0 += v.y; az0 += v.z; aw0 += v.w;
        }
        e += 8;
        if (e < end) {
            float4 v = *(const float4*)(in + (size_t)sorted[e] * N_UNITS + q * 4);
            ax1 += v.x; ay1 += v.y; az1 += v.z; aw1 += v.w;
        }
        float sx = ax0 + ax1, sy = ay0 + ay1, sz = az0 + az1, sw = aw0 + aw1;
        #pragma unroll
        for (int st = 8; st < 64; st <<= 1) {
            sx += __shfl_xor(sx, st, 64);
            sy += __shfl_xor(sy, st, 64);
            sz += __shfl_xor(sz, st, 64);
            sw += __shfl_xor(sw, st, 64);
        }
        if (eo == 0 && n < N_NODES) {
            if (LAYER1) {
                float ii = rsqrtf(fmaxf((float)(end - beg), 1.0f));
                float io = rsqrtf(fmaxf((float)outdegI[n], 1.0f));
                float4 r;
                r.x = fmaxf(fmaf(sx, ii, b1s[q * 4 + 0]), 0.0f) * io;
                r.y = fmaxf(fmaf(sy, ii, b1s[q * 4 + 1]), 0.0f) * io;
                r.z = fmaxf(fmaf(sz, ii, b1s[q * 4 + 2]), 0.0f) * io;
                r.w = fmaxf(fmaf(sw, ii, b1s[q * 4 + 3]), 0.0f) * io;
                *(float4*)(outbuf + (size_t)n * N_UNITS + q * 4) = r;
                if (q == 0) inv_in[n] = ii;
            } else {
                *(float4*)(outbuf + (size_t)n * N_UNITS + q * 4) =
                    make_float4(sx, sy, sz, sw);
            }
        }
    }
}

// ================= K7: v = (agg2 @ W2)*inv_in + b2 ; out = log_softmax(v) =================
__global__ void __launch_bounds__(256) finalize_kernel(
        const float* __restrict__ agg2, const float* __restrict__ inv_in,
        const float* __restrict__ W2, const float* __restrict__ b2,
        float* __restrict__ out, int N) {
    __shared__ float W2s[N_UNITS * OUT_FEATS];
    __shared__ float b2s[OUT_FEATS];
    for (int i = threadIdx.x; i < N_UNITS * OUT_FEATS; i += 256) W2s[i] = W2[i];
    if (threadIdx.x < OUT_FEATS) b2s[threadIdx.x] = b2[threadIdx.x];
    __syncthreads();
    int n = blockIdx.x * 256 + threadIdx.x;
    if (n >= N) return;
    float a[N_UNITS];
    const float4* ar = (const float4*)(agg2 + (size_t)n * N_UNITS);
    #pragma unroll
    for (int qq = 0; qq < N_UNITS / 4; ++qq) {
        float4 v = ar[qq];
        a[qq * 4 + 0] = v.x; a[qq * 4 + 1] = v.y; a[qq * 4 + 2] = v.z; a[qq * 4 + 3] = v.w;
    }
    float ii = inv_in[n];
    float s[OUT_FEATS];
    #pragma unroll
    for (int o = 0; o < OUT_FEATS; ++o) s[o] = 0.0f;
    #pragma unroll
    for (int k = 0; k < N_UNITS; ++k) {
        float ak = a[k];
        #pragma unroll
        for (int o = 0; o < OUT_FEATS; ++o) s[o] = fmaf(ak, W2s[k * OUT_FEATS + o], s[o]);
    }
    float mx = -INFINITY;
    #pragma unroll
    for (int o = 0; o < OUT_FEATS; ++o) {
        s[o] = fmaf(s[o], ii, b2s[o]);
        mx = fmaxf(mx, s[o]);
    }
    float sum = 0.0f;
    #pragma unroll
    for (int o = 0; o < OUT_FEATS; ++o) sum += __expf(s[o] - mx);
    float lse = mx + __logf(sum);
    #pragma unroll
    for (int o = 0; o < OUT_FEATS; ++o) s[o] -= lse;
    float4* orow4 = (float4*)(out + (size_t)n * OUT_FEATS);
    #pragma unroll
    for (int qq = 0; qq < OUT_FEATS / 4; ++qq)
        orow4[qq] = make_float4(s[qq * 4], s[qq * 4 + 1], s[qq * 4 + 2], s[qq * 4 + 3]);
}

extern "C" void kernel_launch(void* const* d_in, const int* in_sizes, int n_in,
                              void* d_out, int out_size, void* d_ws, size_t ws_size,
                              hipStream_t stream) {
    const float* x   = (const float*)d_in[0];
    const float* W1  = (const float*)d_in[1];
    const float* b1  = (const float*)d_in[2];
    const float* W2  = (const float*)d_in[3];
    const float* b2  = (const float*)d_in[4];
    const int*   src = (const int*)d_in[5];
    const int*   dst = (const int*)d_in[6];
    float* out = (float*)d_out;

    // -------- workspace layout --------
    char* base = (char*)d_ws;
    int*      outdegI      = (int*)(base);                  // [N]      400000 B
    int*      bucket_count = (int*)(base + 400000L);        // [NB]     (slot to 408192)
    int*      gbaseA       = (int*)(base + 406400L);        // [NC+1]
    int*      gcursorA     = (int*)(base + 406912L);        // [NC]
    int*      gbase        = (int*)(base + 408192L);        // [NB+1]   8192 B slot
    int*      gcursor      = (int*)(base + 416384L);        // [NB]     8192 B slot
    float*    inv_in       = (float*)(base + 424576L);      // [N]      400000 B
    unsigned* pairs        = (unsigned*)(base + 824576L);   // [E]      12.8 MB
    float*    h            = (float*)(base + 13624576L);    // [N*32] — aliased by pairsA
    float*    rprime       = (float*)(base + 26424576L);    // [N*32] — aliased by partials
    float*    agg2         = (float*)(base + 39224576L);    // [N*32]
    unsigned* pairsA       = (unsigned*)h;                  // dead before gemm1 writes h
    int*      partials     = (int*)rprime;                  // [NSL*OD_STRIPES*ODS] = 10.2 MB, dead before gather1

    // zero bucket_count slot only (outdegI fully written by reduce)
    hipMemsetAsync(bucket_count, 0, 8192L, stream);

    outdeg_hist_kernel<<<NSL * OD_STRIPES, 256, 0, stream>>>(src, partials);
    outdeg_reduce_kernel<<<(N_NODES + 255) / 256, 256, 0, stream>>>(partials, outdegI);

    count_kernel<<<128, 256, 0, stream>>>(dst, bucket_count);
    scan_kernel<<<1, 1024, 0, stream>>>(bucket_count, gbase, gcursor, gbaseA, gcursorA);
    binA_kernel<<<NBLK, 512, 0, stream>>>(src, dst, gcursorA, pairsA);
    binB_kernel<<<NBLK, 512, 0, stream>>>(pairsA, gbaseA, gcursor, pairs);

    gemm1_kernel<<<(N_NODES * 4 + 255) / 256, 256, 0, stream>>>(x, W1, outdegI, h, N_NODES);

    gather_kernel<true><<<NB, 256, 0, stream>>>(h, pairs, gbase, outdegI, b1, rprime, inv_in);
    gather_kernel<false><<<NB, 256, 0, stream>>>(rprime, pairs, gbase, outdegI, b1, agg2, inv_in);

    finalize_kernel<<<(N_NODES + 255) / 256, 256, 0, stream>>>(agg2, inv_in, W2, b2, out, N_NODES);
}

// Round 7
// 392.315 us; speedup vs baseline: 1.2420x; 1.1195x over previous
//
#include <hip/hip_runtime.h>
#include <hip/hip_bf16.h>
#include <math.h>

#define N_NODES 100000
#define N_EDGES 3200000
#define IN_FEATS 256
#define N_UNITS 32
#define OUT_FEATS 40

#define NPB 64                       // nodes per fine bucket
#define BSHIFT 6                     // dst >> 6 = fine bucket
#define NB 1563                      // ceil(100000/64) fine buckets
#define CAP 4096                     // max edges per fine bucket (avg 2048)

#define NC 49                        // coarse buckets (2048 nodes each)
#define CSHIFT 11                    // dst >> 11 = coarse bucket
#define CHUNK 8192                   // edges per bin block
#define NBLK ((N_EDGES + CHUNK - 1) / CHUNK)   // 391
#define WIN 128                      // fine-bucket window in pass B

// outdeg: 8-bit packed LDS counters (max deg ~60 << 255), 2 slices x 192 stripes
#define ODS2 65536                   // nodes per slice (64 KB LDS of bytes)
#define OD_WORDS 16384               // ODS2/4 packed words
#define OD_NSL 2
#define OD_S 192

// ================= K0a: outdeg histogram — 8-bit packed, slice-filtered =================
__global__ void __launch_bounds__(256) outdeg_hist_kernel(const int* __restrict__ src,
                                                          unsigned* __restrict__ partials) {
    __shared__ unsigned lh[OD_WORDS];        // 64 KB: 65536 byte counters
    int slice = blockIdx.x / OD_S;
    int stripe = blockIdx.x % OD_S;
    for (int i = threadIdx.x; i < OD_WORDS; i += 256) lh[i] = 0;
    __syncthreads();
    int lo = slice * ODS2;
    const int4* s4 = (const int4*)src;
    const int total4 = N_EDGES / 4;
    for (int i = stripe * 256 + threadIdx.x; i < total4; i += OD_S * 256) {
        int4 v = s4[i];
        unsigned a = (unsigned)(v.x - lo); if (a < ODS2) atomicAdd(&lh[a >> 2], 1u << ((a & 3) * 8));
        unsigned b = (unsigned)(v.y - lo); if (b < ODS2) atomicAdd(&lh[b >> 2], 1u << ((b & 3) * 8));
        unsigned c = (unsigned)(v.z - lo); if (c < ODS2) atomicAdd(&lh[c >> 2], 1u << ((c & 3) * 8));
        unsigned d = (unsigned)(v.w - lo); if (d < ODS2) atomicAdd(&lh[d >> 2], 1u << ((d & 3) * 8));
    }
    __syncthreads();
    unsigned* dstp = partials + (size_t)blockIdx.x * OD_WORDS;
    for (int i = threadIdx.x; i < OD_WORDS; i += 256) dstp[i] = lh[i];
}

// ================= K0b: SWAR reduce partials -> inv_out (float) =================
// thread = 4 nodes; byte lanes sum independently across stripes (no carry: deg < 256)
__global__ void __launch_bounds__(256) outdeg_reduce_kernel(const unsigned* __restrict__ partials,
                                                            float* __restrict__ inv_out) {
    int i = blockIdx.x * 256 + threadIdx.x;          // word index = node/4
    if (i >= N_NODES / 4) return;
    int slice = i >> 14;                              // i / OD_WORDS
    int w = i & (OD_WORDS - 1);
    const unsigned* p = partials + (size_t)slice * OD_S * OD_WORDS + w;
    unsigned s = 0;
    #pragma unroll 8
    for (int j = 0; j < OD_S; ++j) s += p[(size_t)j * OD_WORDS];
    float4 r;
    r.x = rsqrtf(fmaxf((float)(s & 0xFF), 1.0f));
    r.y = rsqrtf(fmaxf((float)((s >> 8) & 0xFF), 1.0f));
    r.z = rsqrtf(fmaxf((float)((s >> 16) & 0xFF), 1.0f));
    r.w = rsqrtf(fmaxf((float)(s >> 24), 1.0f));
    *(float4*)(inv_out + 4 * i) = r;
}

// ================= K1: per-fine-bucket edge counts (LDS-aggregated) =================
__global__ void __launch_bounds__(256) count_kernel(const int* __restrict__ dst,
                                                    int* __restrict__ bucket_count) {
    __shared__ int lh[NB];
    for (int i = threadIdx.x; i < NB; i += 256) lh[i] = 0;
    __syncthreads();
    const int4* d4 = (const int4*)dst;
    const int total4 = N_EDGES / 4;
    for (int i = blockIdx.x * 256 + threadIdx.x; i < total4; i += gridDim.x * 256) {
        int4 v = d4[i];
        atomicAdd(&lh[v.x >> BSHIFT], 1);
        atomicAdd(&lh[v.y >> BSHIFT], 1);
        atomicAdd(&lh[v.z >> BSHIFT], 1);
        atomicAdd(&lh[v.w >> BSHIFT], 1);
    }
    __syncthreads();
    for (int i = threadIdx.x; i < NB; i += 256)
        if (lh[i]) atomicAdd(&bucket_count[i], lh[i]);
}

// ================= K2: exclusive scan of fine counts; derive coarse bases =================
__global__ void __launch_bounds__(1024) scan_kernel(const int* __restrict__ bucket_count,
                                                    int* __restrict__ gbase,
                                                    int* __restrict__ gcursor,
                                                    int* __restrict__ gbaseA,
                                                    int* __restrict__ gcursorA) {
    __shared__ int ps[1024];
    int t = threadIdx.x;
    int i0 = 2 * t, i1 = 2 * t + 1;
    int a = (i0 < NB) ? bucket_count[i0] : 0;
    int b = (i1 < NB) ? bucket_count[i1] : 0;
    ps[t] = a + b;
    __syncthreads();
    for (int off = 1; off < 1024; off <<= 1) {
        int v = (t >= off) ? ps[t - off] : 0;
        __syncthreads();
        ps[t] += v;
        __syncthreads();
    }
    int excl = ps[t] - (a + b);
    if (i0 < NB) { gbase[i0] = excl; gcursor[i0] = excl; }
    if (i1 <= NB) { gbase[i1] = excl + a; if (i1 < NB) gcursor[i1] = excl + a; }
    __syncthreads();
    if (t < NC) { int v = gbase[t * 32]; gbaseA[t] = v; gcursorA[t] = v; }
    if (t == NC) gbaseA[NC] = N_EDGES;
}

// ================= K3a: coarse binning (49 bins) — LDS sort + coalesced write =================
// pairsA word: src (17 bits) | dlocal11 (11 bits) << 17
__global__ void __launch_bounds__(512) binA_kernel(const int* __restrict__ src,
                                                   const int* __restrict__ dst,
                                                   int* __restrict__ gcursorA,
                                                   unsigned* __restrict__ pairsA) {
    __shared__ unsigned sortedA[CHUNK];      // 32 KB
    __shared__ int hist[NC];
    __shared__ int lstart[NC];
    __shared__ int cur[NC];
    __shared__ int gres[NC];
    int tid = threadIdx.x;
    int e0 = blockIdx.x * CHUNK;
    int cnt = min(CHUNK, N_EDGES - e0);
    unsigned es[16], ed[16];
    #pragma unroll
    for (int r = 0; r < 16; ++r) {
        int idx = tid + 512 * r;
        if (idx < cnt) { es[r] = src[e0 + idx]; ed[r] = dst[e0 + idx]; }
    }
    if (tid < NC) hist[tid] = 0;
    __syncthreads();
    #pragma unroll
    for (int r = 0; r < 16; ++r) {
        int idx = tid + 512 * r;
        if (idx < cnt) atomicAdd(&hist[ed[r] >> CSHIFT], 1);
    }
    __syncthreads();
    if (tid < 64) {
        int v = (tid < NC) ? hist[tid] : 0;
        int inc = v;
        #pragma unroll
        for (int off = 1; off < 64; off <<= 1) {
            int u = __shfl_up(inc, off, 64);
            if ((tid & 63) >= off) inc += u;
        }
        if (tid < NC) {
            int ls = inc - v;
            lstart[tid] = ls;
            cur[tid] = ls;
            gres[tid] = atomicAdd(&gcursorA[tid], v) - ls;   // dest = gres[c] + i
        }
    }
    __syncthreads();
    #pragma unroll
    for (int r = 0; r < 16; ++r) {
        int idx = tid + 512 * r;
        if (idx < cnt) {
            int c = ed[r] >> CSHIFT;
            int pos = atomicAdd(&cur[c], 1);
            sortedA[pos] = es[r] | ((ed[r] & ((1u << CSHIFT) - 1)) << 17);
        }
    }
    __syncthreads();
    for (int i = tid; i < cnt; i += 512) {
        int lo = 0, hi = NC - 1;                // largest c with lstart[c] <= i
        while (lo < hi) { int mid = (lo + hi + 1) >> 1; if (lstart[mid] <= i) lo = mid; else hi = mid - 1; }
        pairsA[gres[lo] + i] = sortedA[i];
    }
}

// ================= K3b: fine binning within 128-bin window — LDS sort + coalesced write =================
// pairs word: src (low 24) | d6 << 24
__global__ void __launch_bounds__(512) binB_kernel(const unsigned* __restrict__ pairsA,
                                                   const int* __restrict__ gbaseA,
                                                   int* __restrict__ gcursor,
                                                   unsigned* __restrict__ pairs) {
    __shared__ unsigned sortedB[CHUNK];      // 32 KB
    __shared__ int hist[WIN];
    __shared__ int lstart[WIN];
    __shared__ int cur[WIN];
    __shared__ int gres[WIN];
    __shared__ int gA[NC + 1];
    int tid = threadIdx.x;
    if (tid <= NC) gA[tid] = gbaseA[tid];
    if (tid < WIN) hist[tid] = 0;
    int e0 = blockIdx.x * CHUNK;
    int cnt = min(CHUNK, N_EDGES - e0);
    __syncthreads();
    int c0 = 0;
    { int lo = 0, hi = NC - 1;
      while (lo < hi) { int mid = (lo + hi + 1) >> 1; if (gA[mid] <= e0) lo = mid; else hi = mid - 1; }
      c0 = lo; }
    int w0 = c0 * 32;
    unsigned pv[16]; short fw[16];
    int c = c0;
    #pragma unroll
    for (int r = 0; r < 16; ++r) {
        int idx = tid + 512 * r;
        if (idx < cnt) {
            int pos = e0 + idx;
            while (pos >= gA[c + 1]) ++c;
            unsigned p = pairsA[pos];
            unsigned srcid = p & 0x1FFFF;
            unsigned dl11 = (p >> 17) & 0x7FF;
            int wi = (c - c0) * 32 + (int)(dl11 >> 6);
            atomicAdd(&hist[wi], 1);
            pv[r] = srcid | ((dl11 & 63u) << 24);
            fw[r] = (short)wi;
        }
    }
    __syncthreads();
    if (tid < 64) {
        int v0 = hist[2 * tid], v1 = hist[2 * tid + 1];
        int s = v0 + v1;
        int inc = s;
        #pragma unroll
        for (int off = 1; off < 64; off <<= 1) {
            int u = __shfl_up(inc, off, 64);
            if ((tid & 63) >= off) inc += u;
        }
        int excl = inc - s;
        lstart[2 * tid] = excl;      cur[2 * tid] = excl;
        lstart[2 * tid + 1] = excl + v0; cur[2 * tid + 1] = excl + v0;
        int f0 = w0 + 2 * tid, f1 = f0 + 1;
        gres[2 * tid]     = (f0 < NB) ? (atomicAdd(&gcursor[f0], v0) - excl) : 0;
        gres[2 * tid + 1] = (f1 < NB) ? (atomicAdd(&gcursor[f1], v1) - (excl + v0)) : 0;
    }
    __syncthreads();
    #pragma unroll
    for (int r = 0; r < 16; ++r) {
        int idx = tid + 512 * r;
        if (idx < cnt) {
            int pos = atomicAdd(&cur[fw[r]], 1);
            sortedB[pos] = pv[r];
        }
    }
    __syncthreads();
    for (int i = tid; i < cnt; i += 512) {
        int lo = 0, hi = WIN - 1;
        while (lo < hi) { int mid = (lo + hi + 1) >> 1; if (lstart[mid] <= i) lo = mid; else hi = mid - 1; }
        pairs[gres[lo] + i] = sortedB[i];
    }
}

// ================= K4: h[n,32] = (x[n,:] @ W1) * inv_out[n] =================
__global__ void __launch_bounds__(256) gemm1_kernel(
        const float* __restrict__ x, const float* __restrict__ W1,
        const float* __restrict__ inv_out, float* __restrict__ h, int N) {
    __shared__ float Ws[IN_FEATS * N_UNITS];  // 32 KB
    for (int idx = threadIdx.x; idx < IN_FEATS * N_UNITS; idx += 256)
        Ws[idx] = W1[idx];
    __syncthreads();
    unsigned t = blockIdx.x * 256 + threadIdx.x;
    unsigned n = t >> 2;
    if (n >= (unsigned)N) return;
    unsigned j0 = (t & 3) * 8;
    float acc[8] = {0, 0, 0, 0, 0, 0, 0, 0};
    const float4* xr = (const float4*)(x + (size_t)n * IN_FEATS);
    #pragma unroll 4
    for (int k4 = 0; k4 < IN_FEATS / 4; ++k4) {
        float4 xv = xr[k4];
        const float* wk = Ws + (k4 * 4) * N_UNITS + j0;
        #pragma unroll
        for (int jj = 0; jj < 8; ++jj) acc[jj] = fmaf(xv.x, wk[jj], acc[jj]);
        #pragma unroll
        for (int jj = 0; jj < 8; ++jj) acc[jj] = fmaf(xv.y, wk[N_UNITS + jj], acc[jj]);
        #pragma unroll
        for (int jj = 0; jj < 8; ++jj) acc[jj] = fmaf(xv.z, wk[2 * N_UNITS + jj], acc[jj]);
        #pragma unroll
        for (int jj = 0; jj < 8; ++jj) acc[jj] = fmaf(xv.w, wk[3 * N_UNITS + jj], acc[jj]);
    }
    float io = inv_out[n];
    float* hr = h + (size_t)n * N_UNITS + j0;
    #pragma unroll
    for (int jj = 0; jj < 8; ++jj) hr[jj] = acc[jj] * io;
}

// ================= K5/K6: bucketed gather — LDS counting sort + register accumulation =================
template <bool LAYER1>
__global__ void __launch_bounds__(256) gather_kernel(
        const float* __restrict__ in, const unsigned* __restrict__ pairs,
        const int* __restrict__ gbase, const float* __restrict__ inv_out,
        const float* __restrict__ b1, float* __restrict__ outbuf,
        float* __restrict__ inv_in) {
    __shared__ int sorted[CAP];        // 16 KB: src ids grouped by local dst
    __shared__ int cnt[NPB];
    __shared__ int start[NPB + 1];
    __shared__ int cur[NPB];
    __shared__ float b1s[N_UNITS];
    int tid = threadIdx.x;
    int b = blockIdx.x;
    int ebeg = gbase[b];
    int ecnt = min(gbase[b + 1] - ebeg, CAP);
    if (tid < NPB) cnt[tid] = 0;
    if (LAYER1 && tid < N_UNITS) b1s[tid] = b1[tid];
    __syncthreads();

    unsigned stash[16];
    #pragma unroll
    for (int r = 0; r < 16; ++r) {
        int idx = tid + 256 * r;
        if (idx < ecnt) {
            unsigned p = pairs[ebeg + idx];
            stash[r] = p;
            atomicAdd(&cnt[p >> 24], 1);
        }
    }
    __syncthreads();

    if (tid < 64) {
        int v = cnt[tid];
        int inc = v;
        #pragma unroll
        for (int off = 1; off < 64; off <<= 1) {
            int u = __shfl_up(inc, off, 64);
            if (tid >= off) inc += u;
        }
        start[tid + 1] = inc;
        cur[tid] = inc - v;
        if (tid == 0) start[0] = 0;
    }
    __syncthreads();

    #pragma unroll
    for (int r = 0; r < 16; ++r) {
        int idx = tid + 256 * r;
        if (idx < ecnt) {
            unsigned p = stash[r];
            int pos = atomicAdd(&cur[p >> 24], 1);
            sorted[pos] = (int)(p & 0xFFFFFF);
        }
    }
    __syncthreads();

    int w = tid >> 6;
    int lane = tid & 63;
    int q = lane & 7;
    int eo = lane >> 3;
    int nd0 = b * NPB;
    #pragma unroll 1
    for (int p = 0; p < 16; ++p) {
        int nd = w * 16 + p;
        int n = nd0 + nd;
        int beg = start[nd];
        int end = start[nd + 1];
        float ax0 = 0.f, ay0 = 0.f, az0 = 0.f, aw0 = 0.f;
        float ax1 = 0.f, ay1 = 0.f, az1 = 0.f, aw1 = 0.f;
        int e = beg + eo;
        for (; e + 8 < end; e += 16) {
            int s0 = sorted[e];
            int s1 = sorted[e + 8];
            float4 v0 = *(const float4*)(in + (size_t)s0 * N_UNITS + q * 4);
            float4 v1 = *(const float4*)(in + (size_t)s1 * N_UNITS + q * 4);
            ax0 += v0.x; ay0 += v0.y; az0 += v0.z; aw0 += v0.w;
            ax1 += v1.x; ay1 += v1.y; az1 += v1.z; aw1 += v1.w;
        }
        if (e < end) {
            float4 v = *(const float4*)(in + (size_t)sorted[e] * N_UNITS + q * 4);
            ax0 += v.x; ay0 += v.y; az0 += v.z; aw0 += v.w;
        }
        e += 8;
        if (e < end) {
            float4 v = *(const float4*)(in + (size_t)sorted[e] * N_UNITS + q * 4);
            ax1 += v.x; ay1 += v.y; az1 += v.z; aw1 += v.w;
        }
        float sx = ax0 + ax1, sy = ay0 + ay1, sz = az0 + az1, sw = aw0 + aw1;
        #pragma unroll
        for (int st = 8; st < 64; st <<= 1) {
            sx += __shfl_xor(sx, st, 64);
            sy += __shfl_xor(sy, st, 64);
            sz += __shfl_xor(sz, st, 64);
            sw += __shfl_xor(sw, st, 64);
        }
        if (eo == 0 && n < N_NODES) {
            if (LAYER1) {
                float ii = rsqrtf(fmaxf((float)(end - beg), 1.0f));
                float io = inv_out[n];
                float4 r;
                r.x = fmaxf(fmaf(sx, ii, b1s[q * 4 + 0]), 0.0f) * io;
                r.y = fmaxf(fmaf(sy, ii, b1s[q * 4 + 1]), 0.0f) * io;
                r.z = fmaxf(fmaf(sz, ii, b1s[q * 4 + 2]), 0.0f) * io;
                r.w = fmaxf(fmaf(sw, ii, b1s[q * 4 + 3]), 0.0f) * io;
                *(float4*)(outbuf + (size_t)n * N_UNITS + q * 4) = r;
                if (q == 0) inv_in[n] = ii;
            } else {
                *(float4*)(outbuf + (size_t)n * N_UNITS + q * 4) =
                    make_float4(sx, sy, sz, sw);
            }
        }
    }
}

// ================= K7: v = (agg2 @ W2)*inv_in + b2 ; out = log_softmax(v) =================
__global__ void __launch_bounds__(256) finalize_kernel(
        const float* __restrict__ agg2, const float* __restrict__ inv_in,
        const float* __restrict__ W2, const float* __restrict__ b2,
        float* __restrict__ out, int N) {
    __shared__ float W2s[N_UNITS * OUT_FEATS];
    __shared__ float b2s[OUT_FEATS];
    for (int i = threadIdx.x; i < N_UNITS * OUT_FEATS; i += 256) W2s[i] = W2[i];
    if (threadIdx.x < OUT_FEATS) b2s[threadIdx.x] = b2[threadIdx.x];
    __syncthreads();
    int n = blockIdx.x * 256 + threadIdx.x;
    if (n >= N) return;
    float a[N_UNITS];
    const float4* ar = (const float4*)(agg2 + (size_t)n * N_UNITS);
    #pragma unroll
    for (int qq = 0; qq < N_UNITS / 4; ++qq) {
        float4 v = ar[qq];
        a[qq * 4 + 0] = v.x; a[qq * 4 + 1] = v.y; a[qq * 4 + 2] = v.z; a[qq * 4 + 3] = v.w;
    }
    float ii = inv_in[n];
    float s[OUT_FEATS];
    #pragma unroll
    for (int o = 0; o < OUT_FEATS; ++o) s[o] = 0.0f;
    #pragma unroll
    for (int k = 0; k < N_UNITS; ++k) {
        float ak = a[k];
        #pragma unroll
        for (int o = 0; o < OUT_FEATS; ++o) s[o] = fmaf(ak, W2s[k * OUT_FEATS + o], s[o]);
    }
    float mx = -INFINITY;
    #pragma unroll
    for (int o = 0; o < OUT_FEATS; ++o) {
        s[o] = fmaf(s[o], ii, b2s[o]);
        mx = fmaxf(mx, s[o]);
    }
    float sum = 0.0f;
    #pragma unroll
    for (int o = 0; o < OUT_FEATS; ++o) sum += __expf(s[o] - mx);
    float lse = mx + __logf(sum);
    #pragma unroll
    for (int o = 0; o < OUT_FEATS; ++o) s[o] -= lse;
    float4* orow4 = (float4*)(out + (size_t)n * OUT_FEATS);
    #pragma unroll
    for (int qq = 0; qq < OUT_FEATS / 4; ++qq)
        orow4[qq] = make_float4(s[qq * 4], s[qq * 4 + 1], s[qq * 4 + 2], s[qq * 4 + 3]);
}

extern "C" void kernel_launch(void* const* d_in, const int* in_sizes, int n_in,
                              void* d_out, int out_size, void* d_ws, size_t ws_size,
                              hipStream_t stream) {
    const float* x   = (const float*)d_in[0];
    const float* W1  = (const float*)d_in[1];
    const float* b1  = (const float*)d_in[2];
    const float* W2  = (const float*)d_in[3];
    const float* b2  = (const float*)d_in[4];
    const int*   src = (const int*)d_in[5];
    const int*   dst = (const int*)d_in[6];
    float* out = (float*)d_out;

    // -------- workspace layout --------
    char* base = (char*)d_ws;
    float*    inv_out      = (float*)(base);                // [N]      400000 B
    int*      bucket_count = (int*)(base + 400000L);        // [NB]     (slot to 408192)
    int*      gbaseA       = (int*)(base + 406400L);        // [NC+1]
    int*      gcursorA     = (int*)(base + 406912L);        // [NC]
    int*      gbase        = (int*)(base + 408192L);        // [NB+1]   8192 B slot
    int*      gcursor      = (int*)(base + 416384L);        // [NB]     8192 B slot
    float*    inv_in       = (float*)(base + 424576L);      // [N]      400000 B
    unsigned* pairs        = (unsigned*)(base + 824576L);   // [E]      12.8 MB
    float*    h            = (float*)(base + 13624576L);    // [N*32] — aliased by pairsA
    float*    rprime       = (float*)(base + 26424576L);    // [N*32] — aliased by partials (lo)
    float*    agg2         = (float*)(base + 39224576L);    // [N*32] — aliased by partials (hi)
    unsigned* pairsA       = (unsigned*)h;                  // dead before gemm1 writes h
    unsigned* partials     = (unsigned*)rprime;             // 2*192*64 KB = 25.2 MB over rprime+agg2
                                                            // (contiguous; dead before gather1)

    // zero bucket_count slot only
    hipMemsetAsync(bucket_count, 0, 8192L, stream);

    outdeg_hist_kernel<<<OD_NSL * OD_S, 256, 0, stream>>>(src, partials);
    outdeg_reduce_kernel<<<(N_NODES / 4 + 255) / 256, 256, 0, stream>>>(partials, inv_out);

    count_kernel<<<128, 256, 0, stream>>>(dst, bucket_count);
    scan_kernel<<<1, 1024, 0, stream>>>(bucket_count, gbase, gcursor, gbaseA, gcursorA);
    binA_kernel<<<NBLK, 512, 0, stream>>>(src, dst, gcursorA, pairsA);
    binB_kernel<<<NBLK, 512, 0, stream>>>(pairsA, gbaseA, gcursor, pairs);

    gemm1_kernel<<<(N_NODES * 4 + 255) / 256, 256, 0, stream>>>(x, W1, inv_out, h, N_NODES);

    gather_kernel<true><<<NB, 256, 0, stream>>>(h, pairs, gbase, inv_out, b1, rprime, inv_in);
    gather_kernel<false><<<NB, 256, 0, stream>>>(rprime, pairs, gbase, inv_out, b1, agg2, inv_in);

    finalize_kernel<<<(N_NODES + 255) / 256, 256, 0, stream>>>(agg2, inv_in, W2, b2, out, N_NODES);
}